// Round 6
// baseline (362.399 us; speedup 1.0000x reference)
//
#include <hip/hip_runtime.h>

typedef _Float16 f16x4 __attribute__((ext_vector_type(4)));
typedef _Float16 f16x8 __attribute__((ext_vector_type(8)));
typedef float    f32x16 __attribute__((ext_vector_type(16)));

// ---- ws byte offsets ----
#define HN_OFF   0u                       // 8192 fp32: 0.5*||e||^2   (32 KB)
#define BEST_OFF 32768u                   // 8192 u64 packed best     (64 KB)
#define EFH_OFF  98304u                   // e-hi, tile-chunk-major frag layout (2 MB)
#define EFL_OFF  (98304u + 2097152u)      // e-lo * 2^11, same layout
#define XRH_OFF  (98304u + 2u * 2097152u) // x-hi row-major
#define XRL_OFF  (98304u + 3u * 2097152u) // x-lo * 2^11 row-major

// ---- out layout (float indices): [quantized NCHW 1M][encodings 64M] ----
#define OUT_ENC  1048576

// K1': three block roles (all memory-streaming, so they share HBM cleanly):
//   bx <   64 : e-tile convert+transpose to frag layout + 0.5*||e||^2
//   bx < 1088 : x convert (row-major hi/lo planes) + best-init
//   bx < 1600 : pure zero-fill of the 268 MB encodings output (512 KB/block)
// e frag layout (f16x8 granules): tile*2048 + chunk*128 + code
__global__ __launch_bounds__(256) void k1_convert(const float* __restrict__ x,
                                                  const float* __restrict__ e,
                                                  char* __restrict__ wsb,
                                                  float* __restrict__ out) {
    int bx = blockIdx.x, tid = threadIdx.x;
    if (bx >= 1088) {
        // dedicated streaming zero-fill: no coupling with any compute kernel
        int f = bx - 1088;                // 0..511
        float4* enc4 = (float4*)(out + OUT_ENC) + (size_t)f * 32768;
        float4 z4 = make_float4(0.f, 0.f, 0.f, 0.f);
        #pragma unroll
        for (int i = 0; i < 128; i++) enc4[i * 256 + tid] = z4;
        return;
    }
    if (bx < 64) {
        __shared__ f16x8 lds[4096];       // 64 KB: [plane][chunk*128 + (code^chunk)]
        const float* src = e + (size_t)bx * 16384;
        float* hnp = (float*)(wsb + HN_OFF);
        #pragma unroll
        for (int it = 0; it < 8; it++) {
            int g = it * 256 + tid;       // 2048 granules: row = g>>4, c16 = g&15
            int row = g >> 4, c16 = g & 15;
            float4 v0 = *(const float4*)(src + row * 128 + c16 * 8);
            float4 v1 = *(const float4*)(src + row * 128 + c16 * 8 + 4);
            float f[8] = {v0.x, v0.y, v0.z, v0.w, v1.x, v1.y, v1.z, v1.w};
            f16x8 hi, lo;
            float ss = 0.f;
            #pragma unroll
            for (int j = 0; j < 8; j++) {
                hi[j] = (_Float16)f[j];
                lo[j] = (_Float16)((f[j] - (float)hi[j]) * 2048.0f);
                ss += f[j] * f[j];
            }
            int sw = row ^ c16;           // bank swizzle (internal to k1)
            lds[c16 * 128 + sw] = hi;
            lds[2048 + c16 * 128 + sw] = lo;
            #pragma unroll
            for (int o = 8; o > 0; o >>= 1) ss += __shfl_down(ss, o, 16);
            if ((tid & 15) == 0) hnp[bx * 128 + row] = 0.5f * ss;
        }
        __syncthreads();
        _Float16* eh = (_Float16*)(wsb + EFH_OFF);
        _Float16* el = (_Float16*)(wsb + EFL_OFF);
        #pragma unroll
        for (int it = 0; it < 16; it++) {
            int g = it * 256 + tid;       // 4096 out granules
            int plane = g >> 11, gg = g & 2047;
            int chunk = gg >> 7, code = gg & 127;
            f16x8 v = lds[plane * 2048 + chunk * 128 + (code ^ chunk)];
            _Float16* dst = plane ? el : eh;
            *(f16x8*)(dst + ((size_t)bx * 2048 + gg) * 8) = v;
        }
    } else {
        int sec = bx - 64;                // 0..1023
        size_t off = (size_t)sec * 1024 + tid * 4;
        float4 v = *(const float4*)(x + off);
        f16x4 hi, lo;
        hi[0] = (_Float16)v.x; hi[1] = (_Float16)v.y;
        hi[2] = (_Float16)v.z; hi[3] = (_Float16)v.w;
        lo[0] = (_Float16)((v.x - (float)hi[0]) * 2048.0f);
        lo[1] = (_Float16)((v.y - (float)hi[1]) * 2048.0f);
        lo[2] = (_Float16)((v.z - (float)hi[2]) * 2048.0f);
        lo[3] = (_Float16)((v.w - (float)hi[3]) * 2048.0f);
        *(f16x4*)((_Float16*)(wsb + XRH_OFF) + off) = hi;
        *(f16x4*)((_Float16*)(wsb + XRL_OFF) + off) = lo;
        if (sec < 32)
            ((unsigned long long*)(wsb + BEST_OFF))[sec * 256 + tid] = 0ull;
    }
}

// K2: pure 3-product f16-split MFMA argmax (NO global stores in the K-loop —
// barriers drain only the 64 KB/kt LDS staging, m97-style).
// grid (64 row-tiles, 8 code-chunks); block = 128 rows x 1024 codes, 2/CU.
__global__ __launch_bounds__(256, 2) void k2_mfma(char* __restrict__ wsb) {
    __shared__ _Float16 lds_eh[128 * 128];   // 32 KB, XOR-swizzled 16B chunks
    __shared__ _Float16 lds_el[128 * 128];   // 32 KB
    __shared__ float    lds_hn[1024];        // 4 KB

    const _Float16* xrh = (const _Float16*)(wsb + XRH_OFF);
    const _Float16* xrl = (const _Float16*)(wsb + XRL_OFF);
    const _Float16* erh = (const _Float16*)(wsb + EFH_OFF);
    const _Float16* erl = (const _Float16*)(wsb + EFL_OFF);
    const float* hn = (const float*)(wsb + HN_OFF);
    unsigned long long* bestg = (unsigned long long*)(wsb + BEST_OFF);

    int tid = threadIdx.x;
    int lane = tid & 63, wave = tid >> 6;
    int col = lane & 31, half = lane >> 5;
    int bx = blockIdx.x, by = blockIdx.y;
    int r0 = bx * 128;
    int k0g = by * 1024;
    int row = r0 + wave * 32 + col;          // A-operand m = lane&31

    // A fragments in registers for the whole kernel (k = half*8+j per step s)
    f16x8 ah[8], al[8];
    #pragma unroll
    for (int s = 0; s < 8; s++) {
        ah[s] = *(const f16x8*)(xrh + (size_t)row * 128 + s * 16 + half * 8);
        al[s] = *(const f16x8*)(xrl + (size_t)row * 128 + s * 16 + half * 8);
    }

    // stage this chunk's half-norms (1024 fp32)
    *(float4*)(lds_hn + tid * 4) = *(const float4*)(hn + k0g + tid * 4);

    float best[16];
    int bidx[16];
    #pragma unroll
    for (int i = 0; i < 16; i++) { best[i] = -3.0e38f; bidx[i] = 0; }

    for (int kt = 0; kt < 8; kt++) {
        __syncthreads();                      // prev tile consumed (also hn vis)
        // stage e-tile from frag-layout planes (linear granule order):
        // granule g of plane: chunk = g>>7, code = g&127.
        // swizzled LDS dest: code*16 + (chunk ^ (code&15)) granules.
        const f16x8* sh = (const f16x8*)erh + ((size_t)(by * 8 + kt) * 2048);
        const f16x8* sl = (const f16x8*)erl + ((size_t)(by * 8 + kt) * 2048);
        #pragma unroll
        for (int i = 0; i < 16; i++) {
            int g = tid + i * 256;
            int gg = g & 2047;
            int chunk = gg >> 7, code = gg & 127;
            f16x8 v = (i < 8) ? sh[gg] : sl[gg];
            _Float16* dstp = (i < 8) ? lds_eh : lds_el;
            *(f16x8*)(dstp + code * 128 + ((chunk ^ (code & 15)) * 8)) = v;
        }
        __syncthreads();                      // tile visible

        #pragma unroll
        for (int sub = 0; sub < 4; sub++) {
            f32x16 a0, a1, a2;
            #pragma unroll
            for (int i = 0; i < 16; i++) { a0[i] = 0.f; a1[i] = 0.f; a2[i] = 0.f; }
            int cbase = (sub * 32 + col) * 128;   // B n-index = lane&31
            #pragma unroll
            for (int s = 0; s < 8; s++) {
                int so = ((s * 2 + half) ^ (col & 15)) * 8;
                f16x8 bh = *(const f16x8*)(lds_eh + cbase + so);
                f16x8 bl = *(const f16x8*)(lds_el + cbase + so);
                a0 = __builtin_amdgcn_mfma_f32_32x32x16_f16(ah[s], bh, a0, 0, 0, 0);
                a1 = __builtin_amdgcn_mfma_f32_32x32x16_f16(ah[s], bl, a1, 0, 0, 0);
                a2 = __builtin_amdgcn_mfma_f32_32x32x16_f16(al[s], bh, a2, 0, 0, 0);
            }
            int code = k0g + kt * 128 + sub * 32 + col;
            float hnv = lds_hn[kt * 128 + sub * 32 + col];
            #pragma unroll
            for (int r = 0; r < 16; r++) {
                float sc = a0[r] + (a1[r] + a2[r]) * (1.0f / 2048.0f) - hnv;
                if (sc > best[r]) { best[r] = sc; bidx[r] = code; }  // > keeps first
            }
        }
    }

    // reduce across the 32 cols (same half-wave), then device atomicMax.
    // C/D row = (r&3) + 8*(r>>2) + 4*half ; col = lane&31.
    #pragma unroll
    for (int r = 0; r < 16; r++) {
        float s = best[r];
        int bi = bidx[r];
        #pragma unroll
        for (int m = 1; m < 32; m <<= 1) {
            float qs = __shfl_xor(s, m, 64);
            int qi = __shfl_xor(bi, m, 64);
            if (qs > s || (qs == s && qi < bi)) { s = qs; bi = qi; }
        }
        if (col == 0) {
            int rl = (r & 3) + 8 * (r >> 2) + 4 * half;
            unsigned ub = __float_as_uint(s);
            ub = ((int)ub < 0) ? ~ub : (ub | 0x80000000u);   // sortable map
            unsigned long long p = ((unsigned long long)ub << 32) |
                                   (unsigned long long)(0xFFFFFFFFu - (unsigned)bi);
            atomicMax(&bestg[r0 + wave * 32 + rl], p);       // tie -> min idx
        }
    }
}

// K3: decode packed best, write one-hot 1.0, gather e[bi] -> NCHW output.
__global__ __launch_bounds__(256) void k3_final(const char* __restrict__ wsb,
                                                const float* __restrict__ wgt,
                                                float* __restrict__ out) {
    int n = blockIdx.x * 256 + threadIdx.x;   // 0..8191
    unsigned long long p = ((const unsigned long long*)(wsb + BEST_OFF))[n];
    int bi = (int)(0xFFFFFFFFu - (unsigned)(p & 0xFFFFFFFFull));

    out[(size_t)OUT_ENC + (size_t)n * 8192 + bi] = 1.0f;

    // out0[((bq*128 + c)*32 + h)*32 + w], n = bq*1024 + h*32 + w
    int bq = n >> 10, hw = n & 1023;
    float* o = out + (size_t)bq * 131072 + hw;
    const float4* wrow = (const float4*)(wgt + (size_t)bi * 128);
    #pragma unroll
    for (int c4 = 0; c4 < 32; c4++) {
        float4 v = wrow[c4];
        o[(c4 * 4 + 0) * 1024] = v.x;
        o[(c4 * 4 + 1) * 1024] = v.y;
        o[(c4 * 4 + 2) * 1024] = v.z;
        o[(c4 * 4 + 3) * 1024] = v.w;
    }
}

extern "C" void kernel_launch(void* const* d_in, const int* in_sizes, int n_in,
                              void* d_out, int out_size, void* d_ws, size_t ws_size,
                              hipStream_t stream) {
    const float* x = (const float*)d_in[0];   // [8,32,32,128] -> [8192][128]
    const float* e = (const float*)d_in[1];   // [8192][128]
    float* out = (float*)d_out;
    char* ws = (char*)d_ws;

    k1_convert<<<1600, 256, 0, stream>>>(x, e, ws, out);
    k2_mfma<<<dim3(64, 8), 256, 0, stream>>>(ws);
    k3_final<<<32, 256, 0, stream>>>(ws, e, out);
}

// Round 7
// 347.131 us; speedup vs baseline: 1.0440x; 1.0440x over previous
//
#include <hip/hip_runtime.h>

typedef _Float16 f16x4 __attribute__((ext_vector_type(4)));
typedef _Float16 f16x8 __attribute__((ext_vector_type(8)));
typedef float    f32x16 __attribute__((ext_vector_type(16)));

typedef const __attribute__((address_space(1))) unsigned int gu32;
typedef __attribute__((address_space(3))) unsigned int su32;

// ---- ws byte offsets ----
#define HN_OFF   0u                       // 8192 fp32: 0.5*||e||^2   (32 KB)
#define BEST_OFF 32768u                   // 8192 u64 packed best     (64 KB)
#define EFH_OFF  98304u                   // e-hi, PRE-SWIZZLED frag layout (2 MB)
#define EFL_OFF  (98304u + 2097152u)      // e-lo * 2^11, same layout
#define XRH_OFF  (98304u + 2u * 2097152u) // x-hi row-major
#define XRL_OFF  (98304u + 3u * 2097152u) // x-lo * 2^11 row-major

// ---- out layout (float indices): [quantized NCHW 1M][encodings 64M] ----
#define OUT_ENC  1048576

// K0: dedicated streaming zero-fill of the 268 MB encodings. No LDS -> full
// occupancy; pure store stream at HBM write BW.
__global__ __launch_bounds__(256) void k0_fill(float* __restrict__ out) {
    float4* enc4 = (float4*)(out + OUT_ENC) + (size_t)blockIdx.x * 32768;
    float4 z4 = make_float4(0.f, 0.f, 0.f, 0.f);
    #pragma unroll
    for (int i = 0; i < 128; i++) enc4[i * 256 + threadIdx.x] = z4;
}

// K1: bx < 64   : e-tile convert + transpose to PRE-SWIZZLED frag layout
//                 + 0.5*||e||^2
//     bx >= 64  : x convert (row-major hi/lo planes) + best-init
// e frag layout (f16x8 granules within a 128-code tile):
//   granule = code*16 + (chunk ^ (code & 15))    [chunk = 16B-chunk of the row]
// so k2 can stage it LINEARLY via global_load_lds and still get the
// conflict-free XOR-swizzled LDS image.
__global__ __launch_bounds__(256) void k1_convert(const float* __restrict__ x,
                                                  const float* __restrict__ e,
                                                  char* __restrict__ wsb) {
    int bx = blockIdx.x, tid = threadIdx.x;
    if (bx < 64) {
        __shared__ f16x8 lds[4096];       // 64 KB: [plane][chunk*128 + (code^chunk)]
        const float* src = e + (size_t)bx * 16384;
        float* hnp = (float*)(wsb + HN_OFF);
        #pragma unroll
        for (int it = 0; it < 8; it++) {
            int g = it * 256 + tid;       // 2048 granules: row = g>>4, c16 = g&15
            int row = g >> 4, c16 = g & 15;
            float4 v0 = *(const float4*)(src + row * 128 + c16 * 8);
            float4 v1 = *(const float4*)(src + row * 128 + c16 * 8 + 4);
            float f[8] = {v0.x, v0.y, v0.z, v0.w, v1.x, v1.y, v1.z, v1.w};
            f16x8 hi, lo;
            float ss = 0.f;
            #pragma unroll
            for (int j = 0; j < 8; j++) {
                hi[j] = (_Float16)f[j];
                lo[j] = (_Float16)((f[j] - (float)hi[j]) * 2048.0f);
                ss += f[j] * f[j];
            }
            int sw = row ^ c16;           // bank swizzle (internal to k1)
            lds[c16 * 128 + sw] = hi;
            lds[2048 + c16 * 128 + sw] = lo;
            #pragma unroll
            for (int o = 8; o > 0; o >>= 1) ss += __shfl_down(ss, o, 16);
            if ((tid & 15) == 0) hnp[bx * 128 + row] = 0.5f * ss;
        }
        __syncthreads();
        _Float16* eh = (_Float16*)(wsb + EFH_OFF);
        _Float16* el = (_Float16*)(wsb + EFL_OFF);
        #pragma unroll
        for (int it = 0; it < 16; it++) {
            int g = it * 256 + tid;       // 4096 out granules
            int plane = g >> 11, gg = g & 2047;
            int chunk = gg >> 7, code = gg & 127;
            f16x8 v = lds[plane * 2048 + chunk * 128 + (code ^ chunk)];
            _Float16* dst = plane ? el : eh;
            int dstg = code * 16 + (chunk ^ (code & 15));   // pre-swizzled
            *(f16x8*)(dst + ((size_t)bx * 2048 + dstg) * 8) = v;
        }
    } else {
        int sec = bx - 64;                // 0..1023
        size_t off = (size_t)sec * 1024 + tid * 4;
        float4 v = *(const float4*)(x + off);
        f16x4 hi, lo;
        hi[0] = (_Float16)v.x; hi[1] = (_Float16)v.y;
        hi[2] = (_Float16)v.z; hi[3] = (_Float16)v.w;
        lo[0] = (_Float16)((v.x - (float)hi[0]) * 2048.0f);
        lo[1] = (_Float16)((v.y - (float)hi[1]) * 2048.0f);
        lo[2] = (_Float16)((v.z - (float)hi[2]) * 2048.0f);
        lo[3] = (_Float16)((v.w - (float)hi[3]) * 2048.0f);
        *(f16x4*)((_Float16*)(wsb + XRH_OFF) + off) = hi;
        *(f16x4*)((_Float16*)(wsb + XRL_OFF) + off) = lo;
        if (sec < 32)
            ((unsigned long long*)(wsb + BEST_OFF))[sec * 256 + tid] = 0ull;
    }
}

// K2: 3-product f16-split MFMA argmax. grid (64 row-tiles, 8 code-chunks);
// block = 128 rows x 1024 codes, 2 blocks/CU. Staging via width-16
// global_load_lds (zero staging VGPRs -> no spills); ws image is
// pre-swizzled so linear staging lands the conflict-free LDS layout.
__global__ __launch_bounds__(256, 2) void k2_mfma(char* __restrict__ wsb) {
    __shared__ _Float16 lds_eh[128 * 128];   // 32 KB, arrives XOR-swizzled
    __shared__ _Float16 lds_el[128 * 128];   // 32 KB

    const _Float16* xrh = (const _Float16*)(wsb + XRH_OFF);
    const _Float16* xrl = (const _Float16*)(wsb + XRL_OFF);
    const char* erh = (const char*)(wsb + EFH_OFF);
    const char* erl = (const char*)(wsb + EFL_OFF);
    const float* hn = (const float*)(wsb + HN_OFF);
    unsigned long long* bestg = (unsigned long long*)(wsb + BEST_OFF);

    int tid = threadIdx.x;
    int lane = tid & 63, wave = tid >> 6;
    int col = lane & 31, half = lane >> 5;
    int bx = blockIdx.x, by = blockIdx.y;
    int r0 = bx * 128;
    int k0g = by * 1024;
    int row = r0 + wave * 32 + col;          // A-operand m = lane&31

    // A fragments in registers for the whole kernel (k = half*8+j per step s)
    f16x8 ah[8], al[8];
    #pragma unroll
    for (int s = 0; s < 8; s++) {
        ah[s] = *(const f16x8*)(xrh + (size_t)row * 128 + s * 16 + half * 8);
        al[s] = *(const f16x8*)(xrl + (size_t)row * 128 + s * 16 + half * 8);
    }

    float best[16];
    int bidx[16];
    #pragma unroll
    for (int i = 0; i < 16; i++) { best[i] = -3.0e38f; bidx[i] = 0; }

    for (int kt = 0; kt < 8; kt++) {
        __syncthreads();                      // prev tile consumed
        // async stage: 2048 granules/plane, linear; LDS dst = base + lane*16
        {
            const char* sh = erh + (size_t)(by * 8 + kt) * 32768;
            const char* sl = erl + (size_t)(by * 8 + kt) * 32768;
            #pragma unroll
            for (int i = 0; i < 8; i++) {
                int g = tid + i * 256;
                __builtin_amdgcn_global_load_lds(
                    (gu32*)(sh + (size_t)g * 16),
                    (su32*)((char*)lds_eh + (size_t)g * 16), 16, 0, 0);
                __builtin_amdgcn_global_load_lds(
                    (gu32*)(sl + (size_t)g * 16),
                    (su32*)((char*)lds_el + (size_t)g * 16), 16, 0, 0);
            }
        }
        __syncthreads();                      // tile visible (drains vmcnt)

        #pragma unroll
        for (int sub = 0; sub < 4; sub++) {
            f32x16 a0, a1, a2;
            #pragma unroll
            for (int i = 0; i < 16; i++) { a0[i] = 0.f; a1[i] = 0.f; a2[i] = 0.f; }
            int cbase = (sub * 32 + col) * 128;   // B n-index = lane&31
            #pragma unroll
            for (int s = 0; s < 8; s++) {
                int so = ((s * 2 + half) ^ (col & 15)) * 8;
                f16x8 bh = *(const f16x8*)(lds_eh + cbase + so);
                f16x8 bl = *(const f16x8*)(lds_el + cbase + so);
                a0 = __builtin_amdgcn_mfma_f32_32x32x16_f16(ah[s], bh, a0, 0, 0, 0);
                a1 = __builtin_amdgcn_mfma_f32_32x32x16_f16(ah[s], bl, a1, 0, 0, 0);
                a2 = __builtin_amdgcn_mfma_f32_32x32x16_f16(al[s], bh, a2, 0, 0, 0);
            }
            int code = k0g + kt * 128 + sub * 32 + col;
            float hnv = hn[code];             // L2-hot
            #pragma unroll
            for (int r = 0; r < 16; r++) {
                float sc = a0[r] + (a1[r] + a2[r]) * (1.0f / 2048.0f) - hnv;
                if (sc > best[r]) { best[r] = sc; bidx[r] = code; }  // > keeps first
            }
        }
    }

    // reduce across the 32 cols (same half-wave), then device atomicMax.
    // C/D row = (r&3) + 8*(r>>2) + 4*half ; col = lane&31.
    #pragma unroll
    for (int r = 0; r < 16; r++) {
        float s = best[r];
        int bi = bidx[r];
        #pragma unroll
        for (int m = 1; m < 32; m <<= 1) {
            float qs = __shfl_xor(s, m, 64);
            int qi = __shfl_xor(bi, m, 64);
            if (qs > s || (qs == s && qi < bi)) { s = qs; bi = qi; }
        }
        if (col == 0) {
            int rl = (r & 3) + 8 * (r >> 2) + 4 * half;
            unsigned ub = __float_as_uint(s);
            ub = ((int)ub < 0) ? ~ub : (ub | 0x80000000u);   // sortable map
            unsigned long long p = ((unsigned long long)ub << 32) |
                                   (unsigned long long)(0xFFFFFFFFu - (unsigned)bi);
            atomicMax(&bestg[r0 + wave * 32 + rl], p);       // tie -> min idx
        }
    }
}

// K3: decode packed best, write one-hot 1.0, gather e[bi] -> NCHW output.
__global__ __launch_bounds__(256) void k3_final(const char* __restrict__ wsb,
                                                const float* __restrict__ wgt,
                                                float* __restrict__ out) {
    int n = blockIdx.x * 256 + threadIdx.x;   // 0..8191
    unsigned long long p = ((const unsigned long long*)(wsb + BEST_OFF))[n];
    int bi = (int)(0xFFFFFFFFu - (unsigned)(p & 0xFFFFFFFFull));

    out[(size_t)OUT_ENC + (size_t)n * 8192 + bi] = 1.0f;

    // out0[((bq*128 + c)*32 + h)*32 + w], n = bq*1024 + h*32 + w
    int bq = n >> 10, hw = n & 1023;
    float* o = out + (size_t)bq * 131072 + hw;
    const float4* wrow = (const float4*)(wgt + (size_t)bi * 128);
    #pragma unroll
    for (int c4 = 0; c4 < 32; c4++) {
        float4 v = wrow[c4];
        o[(c4 * 4 + 0) * 1024] = v.x;
        o[(c4 * 4 + 1) * 1024] = v.y;
        o[(c4 * 4 + 2) * 1024] = v.z;
        o[(c4 * 4 + 3) * 1024] = v.w;
    }
}

extern "C" void kernel_launch(void* const* d_in, const int* in_sizes, int n_in,
                              void* d_out, int out_size, void* d_ws, size_t ws_size,
                              hipStream_t stream) {
    const float* x = (const float*)d_in[0];   // [8,32,32,128] -> [8192][128]
    const float* e = (const float*)d_in[1];   // [8192][128]
    float* out = (float*)d_out;
    char* ws = (char*)d_ws;

    k0_fill<<<512, 256, 0, stream>>>(out);
    k1_convert<<<1088, 256, 0, stream>>>(x, e, ws);
    k2_mfma<<<dim3(64, 8), 256, 0, stream>>>(ws);
    k3_final<<<32, 256, 0, stream>>>(ws, e, out);
}